// Round 8
// baseline (203.053 us; speedup 1.0000x reference)
//
#include <hip/hip_runtime.h>
#include <hip/hip_bf16.h>
#include <stdint.h>

// Problem constants
#define Bn 16
#define Ln 4096
#define KF 384   // IN_F
#define OF 384   // OUT_F

// GEMM tiling: 128x64 block tile, 4 waves of 64x32, acc[4][2] (32 AGPR)
#define BM 128
#define BN 64
#define BK 64
#define LDX 72   // padded leading dim (elements) for transposed X tile

static constexpr float kScale = 0.051031036307982884f;  // 1/sqrt(384)

typedef __attribute__((ext_vector_type(4))) float f32x4;
typedef __attribute__((ext_vector_type(2))) float f32x2;
typedef __attribute__((ext_vector_type(8))) short short8;   // 8 bf16 (4 VGPR) MFMA A/B frag
typedef __attribute__((ext_vector_type(4))) float floatx4;  // MFMA C/D frag
typedef __attribute__((ext_vector_type(2))) unsigned int uint2v;

__device__ __forceinline__ void gl_lds16(const void* g, void* l) {
  __builtin_amdgcn_global_load_lds(
      (const __attribute__((address_space(1))) unsigned int*)g,
      (__attribute__((address_space(3))) unsigned int*)l, 16, 0, 0);
}

// float -> bf16 bits, round-to-nearest-even (finite inputs only)
__device__ __forceinline__ unsigned int f2bf_bits(float f) {
  union { float f; unsigned int u; } v;
  v.f = f;
  return (v.u + 0x7FFFu + ((v.u >> 16) & 1u)) >> 16;
}
__device__ __forceinline__ unsigned int pack2bf(float lo, float hi) {
  return f2bf_bits(lo) | (f2bf_bits(hi) << 16);
}

// HW packed f32->bf16 (RNE, bit-identical to pack2bf; validated round 3)
__device__ __forceinline__ unsigned int cvt_pk_bf16(float lo, float hi) {
  unsigned int r;
  asm("v_cvt_pk_bf16_f32 %0, %1, %2" : "=v"(r) : "v"(lo), "v"(hi));
  return r;
}

// Kernel 1: wmod[b][o][k] = bf16( SCALE*weight[o][k]*y[b][k] * rsqrt(sum_k(.)^2 + eps) )
__global__ __launch_bounds__(256) void modw_kernel(const float* __restrict__ weight,
                                                   const float* __restrict__ y,
                                                   unsigned short* __restrict__ wmod) {
  int t = threadIdx.x;
  int wv = t >> 6, lane = t & 63;
  int row = blockIdx.x * 4 + wv;  // [0, Bn*OF)
  int b = row / OF, o = row % OF;
  const float* wr = weight + o * KF;
  const float* yr = y + b * KF;
  float vals[6];
  float ss = 0.f;
#pragma unroll
  for (int j = 0; j < 3; ++j) {
    int k = (lane + 64 * j) * 2;
    f32x2 wvv = *(const f32x2*)(wr + k);
    f32x2 yv = *(const f32x2*)(yr + k);
    float t0 = kScale * wvv[0] * yv[0];
    float t1 = kScale * wvv[1] * yv[1];
    vals[2 * j] = t0;
    vals[2 * j + 1] = t1;
    ss += t0 * t0 + t1 * t1;
  }
#pragma unroll
  for (int off = 32; off >= 1; off >>= 1) ss += __shfl_xor(ss, off, 64);
  float d = rsqrtf(ss + 1e-8f);
  unsigned short* orow = wmod + row * KF;
#pragma unroll
  for (int j = 0; j < 3; ++j) {
    int k = (lane + 64 * j) * 2;
    *(unsigned int*)(orow + k) = pack2bf(vals[2 * j] * d, vals[2 * j + 1] * d);
  }
}

// Kernel 2: per batch b: out[o][p] = sum_k wmod[b][o][k] * X[b][k][p]
// OCCUPANCY-4 variant (the r1 goal, done right): shrink the per-wave working
// set instead of fighting the register cap. acc[4][2] = 32 AGPR (wave tile
// 64x32), xv[4]+wv[4], est ~105-110 unified < 128 cap of (256,4) with slack.
// LDS: sA SINGLE-buffered 16KB (DMA timed by r7's counted-vmcnt machinery,
// 2 raw barriers/chunk - barrier count measured free r0 vs r4) + sX dbuf
// 18KB = 34.8KB -> 4 blocks/CU. Net 16 waves/CU vs the 12 every prior
// variant was silently pinned at (VGPR88+AGPR64=152 -> 3 waves/SIMD).
// Grid 3072 (BN=64): 12 sequential blocks/CU, smoother ramp/tail.
// All data-path algebra verbatim from the proven kernel: sA swizzle/DMA
// geometry, sX read-swizzle formula (invariant to new brow), frag k-mapping.
__global__ __launch_bounds__(256, 4) void gemm_kernel(const float* __restrict__ X,
                                                      const unsigned short* __restrict__ Wm,
                                                      float* __restrict__ out) {
  __shared__ unsigned short sA[BM * BK];      // [o][k-chunk swizzled by o&7], 16KB single
  __shared__ unsigned short sX[2][BN * LDX];  // [p][k-chunk swizzled], 9216B each

  // XCD swizzle for 3072 blocks: 3 consecutive logical blocks (same b,nt =>
  // shared X panel) -> same XCD. 3072 = 8 * 384, 384 = 3*128 -> exact.
  int flat = blockIdx.x;                         // 0..3071
  int logical = (flat & 7) * 384 + (flat >> 3);  // bijection
  int mt = logical % 3;
  int nt = (logical / 3) & 63;
  int b = logical / 192;

  int t = threadIdx.x;
  int wave = t >> 6, lane = t & 63;
  int quad = lane >> 4, l15 = lane & 15;

  const float* Xb = X + b * (KF * Ln);
  const unsigned short* Wb = Wm + (b * OF + mt * BM) * KF;
  int pbase = nt * BN;

  floatx4 acc[4][2] = {};

  // X staging: thread owns 4 cols x 4 k-rows (64B fp32).
  int p0 = (t & 15) * 4;     // cols 0..60
  int kr0 = (t >> 4) * 4;    // k-rows 0..60
  // swizzled k-offset: LDS chunk slot c' holds global chunk c'^((p>>2)&7);
  // (p0+j)>>2 == t&15 for j<4, so one offset serves all 4 cols.
  int swk = (((kr0 >> 3) ^ (t & 7)) * 8) + (kr0 & 4);
  int arow = (wave >> 1) * 64 + l15;
  int brow = (wave & 1) * 32 + l15;
  int asw = lane & 7;    // sA read swizzle (= arow&7)
  int xsw = l15 >> 2;    // sX read swizzle base

  // A staging geometry (verbatim r0): 4 waves x 4KB, dest base + lane*16;
  // source k-chunk XOR-permuted so LDS chunk c' holds global chunk c'^(row&7).
  int aoff[4], asrc_row[4], asrc_c[4];
#pragma unroll
  for (int j = 0; j < 4; ++j) {
    int boff = wave * 4096 + j * 1024 + lane * 16;  // byte offset in 16KB tile
    int row = boff >> 7;                            // 128B per row (64 bf16)
    int cp = (boff >> 4) & 7;                       // LDS chunk slot
    aoff[j] = boff;
    asrc_row[j] = row;
    asrc_c[j] = (cp ^ (row & 7)) * 8;               // global k-element offset
  }

  f32x4 xv[4];
  uint2v wv[4];

  // ---- prologue: DMA A(0); load+convert+write X(0); issue X(1); barrier ----
#pragma unroll
  for (int j = 0; j < 4; ++j)
    gl_lds16(Wb + asrc_row[j] * KF + 0 + asrc_c[j], (char*)sA + aoff[j]);
  {
    const float* xsrc = Xb + kr0 * Ln + pbase + p0;
#pragma unroll
    for (int i = 0; i < 4; ++i) xv[i] = *(const f32x4*)(xsrc + i * Ln);
#pragma unroll
    for (int j = 0; j < 4; ++j) {
      wv[j][0] = cvt_pk_bf16(xv[0][j], xv[1][j]);  // auto-waits X(0) (+A(0))
      wv[j][1] = cvt_pk_bf16(xv[2][j], xv[3][j]);
    }
#pragma unroll
    for (int j = 0; j < 4; ++j)
      *(uint2v*)(&sX[0][(p0 + j) * LDX + swk]) = wv[j];
  }
  {
    const float* xsrc = Xb + (BK + kr0) * Ln + pbase + p0;  // X(1), stays in flight
#pragma unroll
    for (int i = 0; i < 4; ++i) xv[i] = *(const f32x4*)(xsrc + i * Ln);
  }
  asm volatile("s_waitcnt lgkmcnt(0)" ::: "memory");
  __builtin_amdgcn_sched_barrier(0);
  __builtin_amdgcn_s_barrier();  // publishes sA(0)+sX(0)

#pragma unroll
  for (int kc = 0; kc < 6; ++kc) {
    int cur = kc & 1;
    // ---- MFMA on current chunk (k = kc*64 + ((s<<2)|quad)*8 + e) ----
#pragma unroll
    for (int s = 0; s < 2; ++s) {
      short8 af[4], bfr[2];
#pragma unroll
      for (int mi = 0; mi < 4; ++mi) {
        int ca = (((s << 2) | quad) ^ asw) * 8;
        af[mi] = *(const short8*)(&sA[(arow + mi * 16) * BK + ca]);
      }
#pragma unroll
      for (int ni = 0; ni < 2; ++ni) {
        int cx = (((s << 2) | quad) ^ ((ni << 2) | xsw)) * 8;
        bfr[ni] = *(const short8*)(&sX[cur][(brow + ni * 16) * LDX + cx]);
      }
      __builtin_amdgcn_s_setprio(1);
#pragma unroll
      for (int mi = 0; mi < 4; ++mi)
#pragma unroll
        for (int ni = 0; ni < 2; ++ni)
          acc[mi][ni] = __builtin_amdgcn_mfma_f32_16x16x32_bf16(af[mi], bfr[ni], acc[mi][ni], 0, 0, 0);
      __builtin_amdgcn_s_setprio(0);
    }
    if (kc < 5) {
      // ---- convert X(kc+1) (only outstanding VMEM -> compiler waits them) ----
#pragma unroll
      for (int j = 0; j < 4; ++j) {
        wv[j][0] = cvt_pk_bf16(xv[0][j], xv[1][j]);
        wv[j][1] = cvt_pk_bf16(xv[2][j], xv[3][j]);
      }
      __builtin_amdgcn_sched_barrier(0);
      __builtin_amdgcn_s_barrier();  // all waves done reading sA(kc)
      __builtin_amdgcn_sched_barrier(0);
      // ---- overwrite sA with chunk kc+1 via DMA [4 vmem, oldest] ----
      int k0n = (kc + 1) * BK;
#pragma unroll
      for (int j = 0; j < 4; ++j)
        gl_lds16(Wb + asrc_row[j] * KF + k0n + asrc_c[j], (char*)sA + aoff[j]);
      // ---- publish-pending sX write for chunk kc+1 ----
#pragma unroll
      for (int j = 0; j < 4; ++j)
        *(uint2v*)(&sX[cur ^ 1][(p0 + j) * LDX + swk]) = wv[j];
      // ---- issue X(kc+2) [4 vmem, newest; survive the barrier] ----
      if (kc < 4) {
        const float* xsrc = Xb + ((kc + 2) * BK + kr0) * Ln + pbase + p0;
#pragma unroll
        for (int i = 0; i < 4; ++i) xv[i] = *(const f32x4*)(xsrc + i * Ln);
        asm volatile("s_waitcnt vmcnt(4)" ::: "memory");  // retire the 4 A-DMAs
      } else {
        asm volatile("s_waitcnt vmcnt(0)" ::: "memory");  // tail: only DMAs in flight
      }
      asm volatile("s_waitcnt lgkmcnt(0)" ::: "memory");  // own ds_writes done
      __builtin_amdgcn_sched_barrier(0);
      __builtin_amdgcn_s_barrier();  // sA(kc+1) + sX(kc+1) ready
    }
  }

  // --- epilogue: C/D layout col=lane&15, row=quad*4+r (proven mapping) ---
  float* outb = out + (b * OF + mt * BM) * Ln + pbase;
#pragma unroll
  for (int mi = 0; mi < 4; ++mi) {
    int ob = (wave >> 1) * 64 + mi * 16 + quad * 4;
#pragma unroll
    for (int ni = 0; ni < 2; ++ni) {
      int p = (wave & 1) * 32 + ni * 16 + l15;
#pragma unroll
      for (int r = 0; r < 4; ++r) outb[(ob + r) * Ln + p] = acc[mi][ni][r];
    }
  }
}

extern "C" void kernel_launch(void* const* d_in, const int* in_sizes, int n_in,
                              void* d_out, int out_size, void* d_ws, size_t ws_size,
                              hipStream_t stream) {
  const float* Efou = (const float*)d_in[0];    // [B, L, IN_F] fp32
  const float* y = (const float*)d_in[1];       // [B, IN_F] fp32
  const float* weight = (const float*)d_in[2];  // [1, OUT_F, IN_F] fp32
  float* out = (float*)d_out;                   // [B*OUT_F*L] fp32 (flat)
  unsigned short* wmod = (unsigned short*)d_ws; // [B, OUT_F, IN_F] bf16, 4.7MB

  modw_kernel<<<(Bn * OF) / 4, 256, 0, stream>>>(weight, y, wmod);
  gemm_kernel<<<Bn * (OF / BM) * (Ln / BN), 256, 0, stream>>>(Efou, wmod, out);
}